// Round 6
// baseline (168.363 us; speedup 1.0000x reference)
//
#include <hip/hip_runtime.h>
#include <hip/hip_bf16.h>

#define Bn   16
#define LATn 512
#define Cn   512
#define Wn   4096
#define Fn   512

using bf16x8 = __attribute__((ext_vector_type(8))) short;
using f32x4  = __attribute__((ext_vector_type(4))) float;

__device__ __forceinline__ unsigned short f2bf(float x) {
    union { float f; unsigned int u; } v; v.f = x;
    unsigned int r = v.u + 0x7fffu + ((v.u >> 16) & 1u);
    return (unsigned short)(r >> 16);
}

__device__ __forceinline__ void gload_lds16(const void* g, void* l) {
    __builtin_amdgcn_global_load_lds(
        (const __attribute__((address_space(1))) unsigned int*)g,
        (__attribute__((address_space(3))) unsigned int*)l, 16, 0, 0);
}

// 1) affine[b][c] = latent . aw[:,c] + ab[c]; 128 blocks, split-K over l
__global__ void k_affine(const float* __restrict__ latent,
                         const float* __restrict__ aw,
                         const float* __restrict__ ab,
                         float* __restrict__ affine,
                         float* __restrict__ zbuf) {
    if (blockIdx.x == 0 && blockIdx.y == 0 && threadIdx.x < 16)
        zbuf[threadIdx.x] = 0.f;
    __shared__ float red[4][64];
    const int t  = threadIdx.x;
    const int cl = t & 63, lq = t >> 6;
    const int c  = blockIdx.x * 64 + cl;
    const int b  = blockIdx.y;
    float s = 0.f;
    #pragma unroll 4
    for (int l = lq * 128; l < lq * 128 + 128; ++l)
        s = fmaf(latent[b * LATn + l], aw[(size_t)l * Cn + c], s);
    red[lq][cl] = s;
    __syncthreads();
    if (t < 64)
        affine[b * Cn + blockIdx.x * 64 + t] =
            red[0][t] + red[1][t] + red[2][t] + red[3][t] + ab[blockIdx.x * 64 + t];
}

// 2a) Q[c][f] = sum_k kw[k][c][f]^2
__global__ void k_qsum(const float* __restrict__ kw, float* __restrict__ Q) {
    const int i = (blockIdx.x * 256 + threadIdx.x) * 4;
    const float4 a = *(const float4*)&kw[i];
    const float4 b = *(const float4*)&kw[Cn * Fn + i];
    const float4 c = *(const float4*)&kw[2 * Cn * Fn + i];
    float4 q;
    q.x = a.x * a.x + b.x * b.x + c.x * c.x;
    q.y = a.y * a.y + b.y * b.y + c.y * c.y;
    q.z = a.z * a.z + b.z * b.z + c.z * c.z;
    q.w = a.w * a.w + b.w * b.w + c.w * c.w;
    *(float4*)&Q[i] = q;
}

// 2b) demod[b][f] = rsqrt(sum_c affine^2 * Q[c][f] + 1e-8); 128 blocks, split-K
__global__ void k_demod2(const float* __restrict__ Q,
                         const float* __restrict__ affine,
                         float* __restrict__ demod) {
    __shared__ float red[4][64];
    const int t  = threadIdx.x;
    const int fl = t & 63, cq = t >> 6;
    const int f  = blockIdx.x * 64 + fl;
    const int b  = blockIdx.y;
    float s = 0.f;
    #pragma unroll 4
    for (int c = cq * 128; c < cq * 128 + 128; ++c) {
        const float a = affine[b * Cn + c];
        s = fmaf(a * a, Q[(size_t)c * Fn + f], s);
    }
    red[cq][fl] = s;
    __syncthreads();
    if (t < 64)
        demod[b * Fn + blockIdx.x * 64 + t] =
            rsqrtf(red[0][t] + red[1][t] + red[2][t] + red[3][t] + 1e-8f);
}

// 3) kt[k][f][c] = bf16(kw[k][c][f])
__global__ void k_tk(const float* __restrict__ kw, unsigned short* __restrict__ kt) {
    __shared__ float lds[32][65];
    const int t  = threadIdx.x;
    const int k  = blockIdx.z;
    const int c0 = blockIdx.x * 32;
    const int f0 = blockIdx.y * 64;
    #pragma unroll
    for (int i = 0; i < 8; ++i) {
        int e = t + 256 * i; int c = e >> 6; int f = e & 63;
        lds[c][f] = kw[((size_t)(k * Cn + c0 + c)) * Fn + f0 + f];
    }
    __syncthreads();
    #pragma unroll
    for (int i = 0; i < 8; ++i) {
        int e = t + 256 * i; int f = e >> 5; int c = e & 31;
        kt[((size_t)(k * Fn + f0 + f)) * Cn + c0 + c] = f2bf(lds[c][f]);
    }
}

// 4) xt[b][w][c] = bf16(content[b][c][w] * affine[b][c])
__global__ void k_tx(const float* __restrict__ content,
                     const float* __restrict__ affine,
                     unsigned short* __restrict__ xt) {
    __shared__ unsigned short lds[64][72];
    const int t  = threadIdx.x;
    const int b  = blockIdx.z;
    const int c0 = blockIdx.y * 64;
    const int w0 = blockIdx.x * 64;
    #pragma unroll
    for (int i = 0; i < 4; ++i) {
        int e = t + 256 * i;
        int c = e >> 4;
        int w4 = (e & 15) * 4;
        float4 v = *(const float4*)&content[((size_t)(b * Cn + c0 + c)) * Wn + w0 + w4];
        float a = affine[b * Cn + c0 + c];
        int wx = w4 ^ ((c >> 3) << 3);
        unsigned short p[4] = {f2bf(v.x * a), f2bf(v.y * a), f2bf(v.z * a), f2bf(v.w * a)};
        *(uint2*)&lds[c][wx] = *(const uint2*)p;
    }
    __syncthreads();
    #pragma unroll
    for (int i = 0; i < 2; ++i) {
        int e = t + 256 * i;
        int w  = e >> 3;
        int q  = e & 7;
        int c8 = q * 8;
        int wx = w ^ (q << 3);
        unsigned short tmp[8];
        #pragma unroll
        for (int j = 0; j < 8; ++j) tmp[j] = lds[c8 + j][wx];
        *(uint4*)&xt[((size_t)b * Wn + w0 + w) * Cn + c0 + c8] = *(uint4*)tmp;
    }
}

// 5) conv-GEMM: 256f x 256w, BK=32, 8 waves, 3 phases/K-tile, counted vmcnt,
//    compiler-scheduled ds_read/MFMA interleave within each phase
#define BM 256
#define BN 256
#define BK 32
#define KBYTES (3 * BM * BK * 2)            // 49152 per buffer
#define BUFB   (KBYTES + BN * BK * 2)       // 65536 per buffer
#define SMEMB  (2 * BUFB + 2 * Cn * 2)      // 133120 total

extern __shared__ __align__(16) char smem[];

// 2 xt chunks per thread for K-slice c0s into buffer dst
#define ISSUE_XT(dst, c0s) { \
    _Pragma("unroll") for (int i_ = 0; i_ < 2; ++i_) { \
        const int Q_ = i_ * 512 + t; \
        const int r_ = Q_ >> 2; \
        const int j_ = (Q_ & 3) ^ ((r_ >> 1) & 3); \
        gload_lds16(&xt[((size_t)b * Wn + w0 + r_) * Cn + (c0s) + j_ * 8], \
                    (dst) + KBYTES + (size_t)Q_ * 16); } }

// 2 kt chunks (plane P) per thread
#define ISSUE_PLANE(dst, c0s, P) { \
    _Pragma("unroll") for (int i_ = 0; i_ < 2; ++i_) { \
        const int Q_ = i_ * 512 + t; \
        const int r_ = Q_ >> 2; \
        const int j_ = (Q_ & 3) ^ ((r_ >> 1) & 3); \
        gload_lds16(&kt[((size_t)((P) * Fn + f0 + r_)) * Cn + (c0s) + j_ * 8], \
                    (dst) + (size_t)((P) * 1024 + Q_) * 16); } }

// one phase = k-tap K: vmcnt(VM) -> barrier -> prefetch issues -> frag reads +
// MFMAs (compiler-scheduled fine-grained lgkmcnt interleave)
#define PHASE(K, VM, ...) { \
    asm volatile("s_waitcnt vmcnt(" #VM ")" ::: "memory"); \
    asm volatile("s_barrier" ::: "memory"); \
    __VA_ARGS__; \
    bf16x8 af[8]; bf16x8 bv[4]; \
    _Pragma("unroll") for (int m_ = 0; m_ < 8; ++m_) { \
        const int r_ = wm * 128 + m_ * 16 + l15; \
        af[m_] = *(const bf16x8*)(ka + ((K) * 256 + r_) * 32 + (lhi ^ ((r_ >> 1) & 3)) * 8); } \
    _Pragma("unroll") for (int n_ = 0; n_ < 4; ++n_) { \
        const int rl_ = wn * 64 + n_ * 16 + l15 + (K) - 1; \
        const unsigned short* bp_ = xa + rl_ * 32 + (lhi ^ ((rl_ >> 1) & 3)) * 8; \
        if ((K) == 0 && n_ == 0 && rl_ < 0)   bp_ = halo + c0 + lhi * 8; \
        if ((K) == 2 && n_ == 3 && rl_ > 255) bp_ = halo + 512 + c0 + lhi * 8; \
        bv[n_] = *(const bf16x8*)bp_; } \
    __builtin_amdgcn_s_setprio(1); \
    _Pragma("unroll") for (int n_ = 0; n_ < 4; ++n_) \
        _Pragma("unroll") for (int m_ = 0; m_ < 8; ++m_) \
            acc[m_][n_] = __builtin_amdgcn_mfma_f32_16x16x32_bf16(af[m_], bv[n_], acc[m_][n_], 0, 0, 0); \
    __builtin_amdgcn_s_setprio(0); }

__global__ __launch_bounds__(512, 1)
void k_conv(const unsigned short* __restrict__ kt,
            const unsigned short* __restrict__ xt,
            const float* __restrict__ demod,
            const float* __restrict__ kb,
            const float* __restrict__ zbuf,
            float* __restrict__ y) {
    const int t  = threadIdx.x;
    const int w0 = blockIdx.x * BN;
    const int f0 = blockIdx.y * BM;
    const int b  = blockIdx.z;

    const int wave = t >> 6;
    const int lane = t & 63;
    const int wm   = wave >> 2;
    const int wn   = wave & 3;
    const int l15  = lane & 15;
    const int lhi  = lane >> 4;

    unsigned short* halo = (unsigned short*)(smem + 2 * BUFB); // [2][512] c-natural

    f32x4 acc[8][4];
    #pragma unroll
    for (int m = 0; m < 8; ++m)
        #pragma unroll
        for (int n = 0; n < 4; ++n)
            #pragma unroll
            for (int r = 0; r < 4; ++r)
                acc[m][n][r] = 0.f;

    // prologue: halo rows (w0-1, w0+BN across all 512 c); drain before tile-0
    // issues so non-issuing waves can safely read halo after the first barrier
    // (raw s_barrier does NOT drain vmcnt).
    if (t < 128) {
        const int h  = t >> 6;
        const int wg = h ? (w0 + BN) : (w0 - 1);
        const unsigned short* src = ((unsigned)wg < (unsigned)Wn)
            ? &xt[((size_t)b * Wn + wg) * Cn + (t & 63) * 8]
            : (const unsigned short*)zbuf;
        gload_lds16(src, halo + (size_t)t * 8);
    }
    asm volatile("s_waitcnt vmcnt(0)" ::: "memory");
    ISSUE_XT(smem, 0);
    ISSUE_PLANE(smem, 0, 0);
    ISSUE_PLANE(smem, 0, 1);
    ISSUE_PLANE(smem, 0, 2);

    int cur = 0;
    for (int cc = 0; cc < Cn / BK; ++cc) {
        const unsigned short* ka = (const unsigned short*)(smem + cur * BUFB);
        const unsigned short* xa = ka + 3 * BM * BK;
        char* nbuf = smem + (cur ^ 1) * BUFB;
        const int c0 = cc * BK;
        const int c1 = c0 + BK;
        const bool pf = cc < Cn / BK - 1;
        // steady-state outstanding at each vmcnt: p0 drains {X,P0} (oldest 4);
        // p1 drains {P1}; p2 drains {P2}. Issue groups are phase-fenced, so
        // only inter-group order matters (intra-group reorder is harmless).
        PHASE(0, 4, if (pf) { ISSUE_XT(nbuf, c1); ISSUE_PLANE(nbuf, c1, 0); });
        PHASE(1, 6, if (pf) { ISSUE_PLANE(nbuf, c1, 1); });
        PHASE(2, 6, if (pf) { ISSUE_PLANE(nbuf, c1, 2); });
        cur ^= 1;
    }

    // epilogue: demod * acc + kb, leaky_relu(0.2)
    #pragma unroll
    for (int m = 0; m < 8; ++m) {
        const int fb = f0 + wm * 128 + m * 16 + lhi * 4;
        const float4 dmv = *(const float4*)&demod[b * Fn + fb];
        const float4 kbv = *(const float4*)&kb[fb];
        const float dmf[4] = {dmv.x, dmv.y, dmv.z, dmv.w};
        const float kbf[4] = {kbv.x, kbv.y, kbv.z, kbv.w};
        #pragma unroll
        for (int n = 0; n < 4; ++n) {
            const int w = w0 + wn * 64 + n * 16 + l15;
            #pragma unroll
            for (int r = 0; r < 4; ++r) {
                float v = fmaf(acc[m][n][r], dmf[r], kbf[r]);
                v = (v >= 0.f) ? v : 0.2f * v;
                y[((size_t)(b * Fn + fb + r)) * Wn + w] = v;
            }
        }
    }
}

extern "C" void kernel_launch(void* const* d_in, const int* in_sizes, int n_in,
                              void* d_out, int out_size, void* d_ws, size_t ws_size,
                              hipStream_t stream) {
    const float* latent  = (const float*)d_in[0];
    const float* content = (const float*)d_in[1];
    const float* aw      = (const float*)d_in[2];
    const float* ab      = (const float*)d_in[3];
    const float* kw      = (const float*)d_in[4];
    const float* kb      = (const float*)d_in[5];
    float* y = (float*)d_out;

    char* ws = (char*)d_ws;
    float*          affine = (float*)(ws);                        // 32 KB
    float*          demod  = (float*)(ws + 32768);                // 32 KB
    float*          zbuf   = (float*)(ws + 65536);                // 64 B (zeroed)
    float*          Q      = (float*)(ws + 131072);               // 1 MB (aliases kt; consumed before k_tk)
    unsigned short* kt     = (unsigned short*)(ws + 131072);      // 1.5 MB
    unsigned short* xt     = (unsigned short*)(ws + 2u * 1024u * 1024u); // 64 MB
    if (ws_size < 2u * 1024u * 1024u + (size_t)Bn * Wn * Cn * 2u) return;

    hipFuncSetAttribute((const void*)k_conv,
                        hipFuncAttributeMaxDynamicSharedMemorySize, SMEMB);

    k_affine<<<dim3(Cn / 64, Bn),           256, 0, stream>>>(latent, aw, ab, affine, zbuf);
    k_qsum  <<<dim3(Cn * Fn / 1024),        256, 0, stream>>>(kw, Q);
    k_demod2<<<dim3(Fn / 64, Bn),           256, 0, stream>>>(Q, affine, demod);
    k_tk    <<<dim3(Cn / 32, Fn / 64, 3),   256, 0, stream>>>(kw, kt);
    k_tx    <<<dim3(Wn / 64, Cn / 64, Bn),  256, 0, stream>>>(content, affine, xt);
    k_conv  <<<dim3(Wn / BN, Fn / BM, Bn),  512, SMEMB, stream>>>(kt, xt, demod, kb, zbuf, y);
}